// Round 3
// baseline (422.740 us; speedup 1.0000x reference)
//
#include <hip/hip_runtime.h>

// Output = conv1x1(x, refine_w, refine_b). Everything else in the reference is
// dead code (`_dead` unused; x_back == x: permutation then its argsort-inverse).
//
// x: (8, 64, 256, 256) fp32, refine_w: (64, 64) [o-major], refine_b: (64,)
// out[b,o,h,w] = sum_c w[o,c] * x[b,c,h,w] + b[o]
//
// v4: rounds 0-2 all plateau at ~1950 GB/s (24% HBM) -- every version batched
// loads then drained vmcnt to 0 before a long FMA block (zero loads in flight
// most of the time). r2's register double-buffer spilled (WRITE_SIZE +65MB).
// Fix: depth via LDS, not VGPRs. global_load_lds (width 16) stages 16-channel
// chunks (16 KB) double-buffered; counted s_waitcnt vmcnt(4) + raw s_barrier
// (T3/T4 pattern) keeps the next chunk's loads in flight across the compute
// phase. Also removes the 4x redundant L1 read (waves share via LDS).
// Accumulation order over c unchanged -> bit-identical to r0/r1.

constexpr int  C      = 64;
constexpr long HW     = 65536;        // 256*256
constexpr long NPIX   = 8L * HW;      // 524288 pixels
constexpr int  P      = 4;            // pixels per thread (float4)
constexpr int  OG     = 4;            // o-groups (one per wave)
constexpr int  OPT    = C / OG;       // 16 output channels per thread
constexpr int  PIXB   = 256;          // pixels per block tile
constexpr int  CCHUNK = 16;           // channels staged per chunk
constexpr int  NCHUNK = C / CCHUNK;   // 4 chunks

typedef float f4 __attribute__((ext_vector_type(4)));

__device__ __forceinline__ void gload_lds16(const float* g, float* l)
{
    // one instr: 64 lanes x 16B -> LDS at (uniform l) + lane*16
    __builtin_amdgcn_global_load_lds(
        (const __attribute__((address_space(1))) unsigned int*)g,
        (__attribute__((address_space(3))) unsigned int*)l,
        16, 0, 0);
}

__global__ __launch_bounds__(256, 4) void conv1x1_refine_kernel(
    const float* __restrict__ x,
    const float* __restrict__ w,     // (64,64) o-major
    const float* __restrict__ bias,  // (64,)
    float* __restrict__ out)
{
    __shared__ float lds[2][CCHUNK][PIXB];   // 2 x 16 KB

    const int t    = threadIdx.x;
    const int lane = t & 63;
    const int og   = __builtin_amdgcn_readfirstlane(t >> 6);  // wave id -> SGPR

    const long pix0 = (long)blockIdx.x * PIXB;   // block's first pixel
    const long b    = pix0 >> 16;                // blocks never straddle a batch
    const long hw0  = pix0 & (HW - 1);

    const float* xb = x + b * ((long)C * HW) + hw0;   // + c*HW + pixel
    float*       ob = out + b * ((long)C * HW) + (long)og * OPT * HW + hw0;
    const float* wg = w + og * OPT * C;               // this wave's 16 rows

    // ---- staging: wave og stages chunk channels [og*4 .. og*4+3] ----
    auto stage = [&](int chunk, int buf) {
#pragma unroll
        for (int k = 0; k < 4; ++k) {
            const int cc = og * 4 + k;                 // channel within chunk
            const int c  = chunk * CCHUNK + cc;
            gload_lds16(xb + (long)c * HW + (long)lane * 4, &lds[buf][cc][0]);
        }
    };

    f4 acc[OPT];
#pragma unroll
    for (int o = 0; o < OPT; ++o) {
        const float bv = bias[og * OPT + o];           // uniform -> s_load
        acc[o] = (f4){bv, bv, bv, bv};
    }

    stage(0, 0);
    stage(1, 1);

#pragma unroll
    for (int cb = 0; cb < NCHUNK; ++cb) {
        // Own 4 loads of chunk cb are the oldest outstanding: counted wait
        // (never drain to 0 while more chunks are in flight -- T4).
        if (cb < NCHUNK - 1) asm volatile("s_waitcnt vmcnt(4)" ::: "memory");
        else                 asm volatile("s_waitcnt vmcnt(0)" ::: "memory");
        __builtin_amdgcn_sched_barrier(0);
        __builtin_amdgcn_s_barrier();     // all waves' chunk-cb loads landed

#pragma unroll
        for (int k = 0; k < CCHUNK; ++k) {
            const int c = cb * CCHUNK + k;
            const f4 xv = *reinterpret_cast<const f4*>(&lds[cb & 1][k][lane * 4]);
#pragma unroll
            for (int o = 0; o < OPT; ++o) {
                const float wv = wg[o * C + c];        // uniform -> SGPR operand
                acc[o].x = fmaf(wv, xv.x, acc[o].x);
                acc[o].y = fmaf(wv, xv.y, acc[o].y);
                acc[o].z = fmaf(wv, xv.z, acc[o].z);
                acc[o].w = fmaf(wv, xv.w, acc[o].w);
            }
        }

        __builtin_amdgcn_s_barrier();     // everyone done reading buf (cb&1)
        if (cb + 2 < NCHUNK) stage(cb + 2, cb & 1);   // overwrite it
    }

    // Streamed output, never re-read: nontemporal keeps x resident in LLC.
#pragma unroll
    for (int o = 0; o < OPT; ++o)
        __builtin_nontemporal_store(acc[o],
            reinterpret_cast<f4*>(ob + (long)o * HW + (long)lane * 4));
}

extern "C" void kernel_launch(void* const* d_in, const int* in_sizes, int n_in,
                              void* d_out, int out_size, void* d_ws, size_t ws_size,
                              hipStream_t stream)
{
    const float* x  = (const float*)d_in[0];   // x
    const float* rw = (const float*)d_in[11];  // refine_w
    const float* rb = (const float*)d_in[12];  // refine_b
    float* out = (float*)d_out;

    const int threads = 256;
    const int blocks  = (int)(NPIX / PIXB);    // 2048
    hipLaunchKernelGGL(conv1x1_refine_kernel, dim3(blocks), dim3(threads), 0, stream,
                       x, rw, rb, out);
}

// Round 4
// 276.483 us; speedup vs baseline: 1.5290x; 1.5290x over previous
//
#include <hip/hip_runtime.h>

// Output = conv1x1(x, refine_w, refine_b). Everything else in the reference is
// dead code (`_dead` unused; x_back == x: permutation then its argsort-inverse).
//
// x: (8, 64, 256, 256) fp32, refine_w: (64, 64) [o-major], refine_b: (64,)
// out[b,o,h,w] = sum_c w[o,c] * x[b,c,h,w] + b[o]
//
// v5: v4's LDS pipeline raised HBM BW 1950->3400 GB/s but spilled acc to
// scratch (WRITE_SIZE 131->587 MB): the asm-"memory" waitcnt fences blocked
// the allocator's AGPR parking that v2 enjoyed (VGPR=56, no spill). Fix both:
//  - 8 waves x 8 output channels -> acc = 32 VGPRs (nothing to park),
//  - plain m97 structure: stage(next) via global_load_lds, compute(cur),
//    __syncthreads(); no inline-asm fences. Cross-block overlap (3 blocks/CU)
//    covers the barrier's vmcnt drain, per m114.
// Accumulation order over c unchanged -> bit-identical results.

constexpr int  C      = 64;
constexpr long HW     = 65536;        // 256*256
constexpr long NPIX   = 8L * HW;      // 524288 pixels
constexpr int  WAVES  = 8;            // 512-thread block
constexpr int  OPT    = C / WAVES;    // 8 output channels per wave
constexpr int  PIXB   = 256;          // pixels per block tile (64 quads)
constexpr int  CCHUNK = 16;           // channels staged per chunk (16 KB)
constexpr int  NCHUNK = C / CCHUNK;   // 4 chunks
constexpr int  CPW    = CCHUNK / WAVES; // 2 channels staged per wave per chunk

typedef float f4 __attribute__((ext_vector_type(4)));

__device__ __forceinline__ void gload_lds16(const float* g, float* l)
{
    // one instr: 64 lanes x 16B contiguous -> LDS at (uniform l) + lane*16
    __builtin_amdgcn_global_load_lds(
        (const __attribute__((address_space(1))) unsigned int*)g,
        (__attribute__((address_space(3))) unsigned int*)l,
        16, 0, 0);
}

__global__ __launch_bounds__(512, 6) void conv1x1_refine_kernel(
    const float* __restrict__ x,
    const float* __restrict__ w,     // (64,64) o-major
    const float* __restrict__ bias,  // (64,)
    float* __restrict__ out)
{
    __shared__ float lds[2][CCHUNK][PIXB];   // 2 x 16 KB

    const int t    = threadIdx.x;
    const int lane = t & 63;
    const int wv   = __builtin_amdgcn_readfirstlane(t >> 6);  // wave id -> SGPR

    const long pix0 = (long)blockIdx.x * PIXB;   // block's first pixel
    const long b    = pix0 >> 16;                // blocks never straddle a batch
    const long hw0  = pix0 & (HW - 1);

    const float* xb = x + b * ((long)C * HW) + hw0;
    float*       ob = out + b * ((long)C * HW) + (long)wv * OPT * HW + hw0;
    const float* wg = w + wv * OPT * C;          // this wave's 8 rows of w

    // wave wv stages chunk channels [wv*2, wv*2+1] (1 KB row each)
    auto stage = [&](int chunk, int buf) {
#pragma unroll
        for (int k = 0; k < CPW; ++k) {
            const int cc = wv * CPW + k;
            const int c  = chunk * CCHUNK + cc;
            gload_lds16(xb + (long)c * HW + (long)lane * 4, &lds[buf][cc][0]);
        }
    };

    f4 acc[OPT];
#pragma unroll
    for (int o = 0; o < OPT; ++o) {
        const float bv = bias[wv * OPT + o];     // uniform -> s_load
        acc[o] = (f4){bv, bv, bv, bv};
    }

    stage(0, 0);
    __syncthreads();                 // vmcnt drain: chunk 0 landed, all waves

#pragma unroll
    for (int cb = 0; cb < NCHUNK; ++cb) {
        // Prefetch next chunk into the other buffer (last read two iters ago,
        // all reads retired at the previous barrier). Loads fly during compute.
        if (cb + 1 < NCHUNK) stage(cb + 1, (cb + 1) & 1);

#pragma unroll
        for (int k = 0; k < CCHUNK; ++k) {
            const int c = cb * CCHUNK + k;
            const f4 xv = *reinterpret_cast<const f4*>(&lds[cb & 1][k][lane * 4]);
#pragma unroll
            for (int o = 0; o < OPT; ++o) {
                const float wvv = wg[o * C + c]; // uniform -> SGPR operand
                acc[o].x = fmaf(wvv, xv.x, acc[o].x);
                acc[o].y = fmaf(wvv, xv.y, acc[o].y);
                acc[o].z = fmaf(wvv, xv.z, acc[o].z);
                acc[o].w = fmaf(wvv, xv.w, acc[o].w);
            }
        }

        __syncthreads();   // next chunk landed + everyone done with this buf
    }

    // Streamed output, never re-read: nontemporal keeps x resident in LLC.
#pragma unroll
    for (int o = 0; o < OPT; ++o)
        __builtin_nontemporal_store(acc[o],
            reinterpret_cast<f4*>(ob + (long)o * HW + (long)lane * 4));
}

extern "C" void kernel_launch(void* const* d_in, const int* in_sizes, int n_in,
                              void* d_out, int out_size, void* d_ws, size_t ws_size,
                              hipStream_t stream)
{
    const float* x  = (const float*)d_in[0];   // x
    const float* rw = (const float*)d_in[11];  // refine_w
    const float* rb = (const float*)d_in[12];  // refine_b
    float* out = (float*)d_out;

    const int threads = 512;
    const int blocks  = (int)(NPIX / PIXB);    // 2048
    hipLaunchKernelGGL(conv1x1_refine_kernel, dim3(blocks), dim3(threads), 0, stream,
                       x, rw, rb, out);
}